// Round 15
// baseline (409.933 us; speedup 1.0000x reference)
//
#include <hip/hip_runtime.h>
#include <hip/hip_bf16.h>
#include <float.h>
#include <math.h>

#define BB 128
#define PP 1024
#define KNN 4
#define NROWS (BB * PP)

typedef __bf16 v8bf __attribute__((ext_vector_type(8)));
typedef float  v4f  __attribute__((ext_vector_type(4)));

__device__ inline unsigned short f2bs(float f) {
    __hip_bfloat16 h = __float2bfloat16(f);
    return *(unsigned short*)&h;
}
__device__ inline unsigned packbf2(float a, float b) {
    return (unsigned)f2bs(a) | ((unsigned)f2bs(b) << 16);
}
// bf16 pair (packed in u32) -> two f32, bit-exact
__device__ inline float bflo(unsigned u) { return __builtin_bit_cast(float, u << 16); }
__device__ inline float bfhi(unsigned u) { return __builtin_bit_cast(float, u & 0xFFFF0000u); }

// sorted-4 insert helper: median-of-3 (single VOP3 on gfx950)
__device__ inline unsigned med3u(unsigned a, unsigned b, unsigned c) {
    unsigned d;
    asm("v_med3_u32 %0, %1, %2, %3" : "=v"(d) : "v"(a), "v"(b), "v"(c));
    return d;
}

// ---------------------------------------------------------------------------
// Pack kernel (raw input x only)
// ---------------------------------------------------------------------------
__global__ __launch_bounds__(256)
void pack_kernel(const float* __restrict__ src, int D,
                 __hip_bfloat16* __restrict__ xh, __hip_bfloat16* __restrict__ xl,
                 float* __restrict__ sq)
{
    const int t = blockIdx.x * 256 + threadIdx.x;     // t < NROWS*4
    const int row = t >> 2, part = t & 3;
    float v[8];
    #pragma unroll
    for (int u = 0; u < 8; u++) {
        int d = part * 8 + u;
        v[u] = (d < D) ? src[(size_t)row * D + d] : 0.f;
    }
    float s = 0.f;
    unsigned int hw[4], lw[4];
    #pragma unroll
    for (int w = 0; w < 4; w++) {
        unsigned short h2[2], l2[2];
        #pragma unroll
        for (int e = 0; e < 2; e++) {
            float x = v[2 * w + e];
            __hip_bfloat16 hb = __float2bfloat16(x);
            float hf = __bfloat162float(hb);
            __hip_bfloat16 lb = __float2bfloat16(x - hf);
            h2[e] = *(unsigned short*)&hb;
            l2[e] = *(unsigned short*)&lb;
            s = fmaf(x, x, s);
        }
        hw[w] = (unsigned int)h2[0] | ((unsigned int)h2[1] << 16);
        lw[w] = (unsigned int)l2[0] | ((unsigned int)l2[1] << 16);
    }
    s += __shfl_xor(s, 1);
    s += __shfl_xor(s, 2);
    uint4 hv; hv.x = hw[0]; hv.y = hw[1]; hv.z = hw[2]; hv.w = hw[3];
    uint4 lv; lv.x = lw[0]; lv.y = lw[1]; lv.z = lw[2]; lv.w = lw[3];
    *(uint4*)&xh[(size_t)row * 32 + part * 8] = hv;
    *(uint4*)&xl[(size_t)row * 32 + part * 8] = lv;
    if (part == 0) sq[row] = s;
}

// ---------------------------------------------------------------------------
// MFMA kNN v12: v11 (swapped-operand, LDS-free main loop) restructured to
// fit the 64-VGPR occupancy bucket (m69: waves/SIMD halve at 64/128/256).
// Wave pair split: (wv>>1) owns a 32-query half, (wv&1) owns a 512-cand
// half -> per-thread query state halves (qh/ql 16 + mn 8 + sqq 2; est ~55
// regs < 64 -> 8 waves/SIMD vs v11's ~80 -> 128-bucket -> 4). Same keys,
// same chains; final merge reads the 8 valid lists per query half.
// ---------------------------------------------------------------------------
__global__ __launch_bounds__(256, 4)
void knn_mfma(const __hip_bfloat16* __restrict__ xh, const __hip_bfloat16* __restrict__ xl,
              const float* __restrict__ sq, int* __restrict__ nidx)
{
    __shared__ unsigned cand[16 * 64];                // 4 KiB

    const int tid = threadIdx.x;
    const int wv = tid >> 6, lane = tid & 63;
    const int lr = lane & 15, lq = lane >> 4;
    const int qsel = wv >> 1;                         // query half (0:rows 0-31, 1:32-63)
    const int csel = wv & 1;                          // candidate half
    const int b = blockIdx.y, i0 = blockIdx.x * 64;
    const size_t Rb = (size_t)b * PP;

    // query fragments (B operand): this thread's queries are qsel*32+it*16+lr
    v8bf qh[2], ql[2];
    #pragma unroll
    for (int it = 0; it < 2; it++) {
        size_t g = Rb + i0 + (qsel * 2 + it) * 16 + lr;
        qh[it] = __builtin_bit_cast(v8bf, *(const uint4*)(xh + g * 32 + lq * 8));
        ql[it] = __builtin_bit_cast(v8bf, *(const uint4*)(xl + g * 32 + lq * 8));
    }
    float sqq[2];
    #pragma unroll
    for (int it = 0; it < 2; it++)
        sqq[it] = sq[Rb + i0 + (qsel * 2 + it) * 16 + lr];

    unsigned mn[2][4];                                // per-query sorted top-4
    #pragma unroll
    for (int it = 0; it < 2; it++)
        #pragma unroll
        for (int s = 0; s < 4; s++) mn[it][s] = ~0u;

    for (int ch = 0; ch < 8; ch++) {
        #pragma unroll
        for (int jt4 = 0; jt4 < 4; jt4++) {
            const int jt = ch * 128 + (csel * 4 + jt4) * 16;  // candidate tile base
            const size_t gj = Rb + jt + lr;                    // A-frag row
            v8bf bh = __builtin_bit_cast(v8bf, *(const uint4*)(xh + gj * 32 + lq * 8));
            v8bf bl = __builtin_bit_cast(v8bf, *(const uint4*)(xl + gj * 32 + lq * 8));
            float4 sqc = *(const float4*)&sq[Rb + jt + lq * 4];
            const float sqcv[4] = {sqc.x, sqc.y, sqc.z, sqc.w};
            #pragma unroll
            for (int it = 0; it < 2; it++) {
                v4f a = (v4f){0.f, 0.f, 0.f, 0.f};
                a = __builtin_amdgcn_mfma_f32_16x16x32_bf16(bl, ql[it], a, 0, 0, 0);
                a = __builtin_amdgcn_mfma_f32_16x16x32_bf16(bl, qh[it], a, 0, 0, 0);
                a = __builtin_amdgcn_mfma_f32_16x16x32_bf16(bh, ql[it], a, 0, 0, 0);
                a = __builtin_amdgcn_mfma_f32_16x16x32_bf16(bh, qh[it], a, 0, 0, 0);
                #pragma unroll
                for (int m = 0; m < 4; m++) {
                    float s = fmaf(-2.f, a[m], sqq[it] + sqcv[m]);  // ||xi-xj||^2
                    s = fmaxf(s, 0.f);
                    unsigned k = (__builtin_bit_cast(unsigned, s) & 0xFFFFFC00u)
                                 | (unsigned)(jt + lq * 4 + m);
                    unsigned n0 = min(mn[it][0], k);
                    unsigned n1 = med3u(mn[it][0], mn[it][1], k);
                    unsigned n2 = med3u(mn[it][1], mn[it][2], k);
                    unsigned n3 = med3u(mn[it][2], mn[it][3], k);
                    mn[it][0] = n0; mn[it][1] = n1; mn[it][2] = n2; mn[it][3] = n3;
                }
            }
        }
    }

    // intra-wave merge across lq (lanes l, l^16, l^32): butterfly.
    #pragma unroll
    for (int d = 16; d <= 32; d <<= 1) {
        #pragma unroll
        for (int it = 0; it < 2; it++) {
            unsigned o0 = __shfl_xor(mn[it][0], d);
            unsigned o1 = __shfl_xor(mn[it][1], d);
            unsigned o2 = __shfl_xor(mn[it][2], d);
            unsigned o3 = __shfl_xor(mn[it][3], d);
            #pragma unroll
            for (int e = 0; e < 4; e++) {
                unsigned k = (e == 0) ? o0 : (e == 1) ? o1 : (e == 2) ? o2 : o3;
                unsigned n0 = min(mn[it][0], k);
                unsigned n1 = med3u(mn[it][0], mn[it][1], k);
                unsigned n2 = med3u(mn[it][1], mn[it][2], k);
                unsigned n3 = med3u(mn[it][2], mn[it][3], k);
                mn[it][0] = n0; mn[it][1] = n1; mn[it][2] = n2; mn[it][3] = n3;
            }
        }
    }

    // cross-wave dump: queries qsel*32 + it*16 + lr; lists wv*4+s.
    // Query cols 0..31 get lists 0..7 (wv 0,1); cols 32..63 get 8..15.
    if (lane < 16) {
        #pragma unroll
        for (int it = 0; it < 2; it++)
            #pragma unroll
            for (int s = 0; s < 4; s++)
                cand[(wv * 4 + s) * 64 + qsel * 32 + it * 16 + lr] = mn[it][s];
    }
    __syncthreads();

    if (tid < 64) {
        const int lbase = (tid >> 5) * 8;             // valid list window
        unsigned g0 = ~0u, g1 = ~0u, g2 = ~0u, g3 = ~0u;
        #pragma unroll
        for (int s2 = 0; s2 < 8; s2++) {
            unsigned k = cand[(lbase + s2) * 64 + tid];
            unsigned n0 = min(g0, k);
            unsigned n1 = med3u(g0, g1, k);
            unsigned n2 = med3u(g1, g2, k);
            unsigned n3 = med3u(g2, g3, k);
            g0 = n0; g1 = n1; g2 = n2; g3 = n3;
        }
        const int base = (int)Rb;
        int* op = nidx + (size_t)(Rb + i0 + tid) * KNN;
        op[0] = base + (int)(g0 & 1023u);
        op[1] = base + (int)(g1 & 1023u);
        op[2] = base + (int)(g2 & 1023u);
        op[3] = base + (int)(g3 & 1023u);
    }
}

// ---------------------------------------------------------------------------
// Edge-MLP v4 (pack fusion, unchanged)
// ---------------------------------------------------------------------------
template<int D, int H, int C, typename OT, bool PACK>
__global__ __launch_bounds__(256, 4)
void edge_mfma(const float* __restrict__ x, const int* __restrict__ nidx,
               const __hip_bfloat16* __restrict__ EW1, const __hip_bfloat16* __restrict__ EW2,
               const float* __restrict__ b1g, const float* __restrict__ b2g,
               OT* __restrict__ out,
               __hip_bfloat16* __restrict__ xhw, __hip_bfloat16* __restrict__ xlw,
               float* __restrict__ sqw)
{
    constexpr int NE = 256;
    constexpr int TDP = (D == 1) ? 32 : 64;
    constexpr int DP  = TDP / 2;
    constexpr int P   = ((TDP > H) ? TDP : H) + 8;
    constexpr int NT1 = H / 16, NT2 = C / 16;
    constexpr int KS1 = TDP / 32, KS2 = H / 32;

    __shared__ __hip_bfloat16 xe[NE * P];

    const int tid = threadIdx.x;
    const int wv = tid >> 6, lane = tid & 63;
    const int lr = lane & 15, q = lane >> 4;
    const int p0 = blockIdx.x * 64;

    {
        const int e = wv * 64 + lane;
        const int j = nidx[(size_t)p0 * KNN + e];
        const int pi = p0 + (e >> 2);
        if constexpr (D == 1) {
            #pragma unroll
            for (int s = 0; s < P / 8; s++) {
                uint4 z; z.x = 0u; z.y = 0u; z.z = 0u; z.w = 0u;
                *(uint4*)&xe[e * P + s * 8] = z;
            }
            xe[e * P + 0]  = __float2bfloat16(x[pi]);
            xe[e * P + DP] = __float2bfloat16(x[j]);
        } else {
            const float* si = x + (size_t)pi * D;
            const float* sj = x + (size_t)j * D;
            #pragma unroll
            for (int s = 0; s < D / 8; s++) {
                float4 f0 = *(const float4*)&si[s * 8];
                float4 f1 = *(const float4*)&si[s * 8 + 4];
                uint4 uv;
                uv.x = packbf2(f0.x, f0.y); uv.y = packbf2(f0.z, f0.w);
                uv.z = packbf2(f1.x, f1.y); uv.w = packbf2(f1.z, f1.w);
                *(uint4*)&xe[e * P + s * 8] = uv;
            }
            #pragma unroll
            for (int s = 0; s < D / 8; s++) {
                float4 f0 = *(const float4*)&sj[s * 8];
                float4 f1 = *(const float4*)&sj[s * 8 + 4];
                uint4 uv;
                uv.x = packbf2(f0.x, f0.y); uv.y = packbf2(f0.z, f0.w);
                uv.z = packbf2(f1.x, f1.y); uv.w = packbf2(f1.z, f1.w);
                *(uint4*)&xe[e * P + DP + s * 8] = uv;
            }
        }
    }

    v4f acc1[4][NT1];
    #pragma unroll
    for (int mi = 0; mi < 4; mi++)
        #pragma unroll
        for (int nt = 0; nt < NT1; nt++) acc1[mi][nt] = (v4f){0.f, 0.f, 0.f, 0.f};

    #pragma unroll
    for (int ks = 0; ks < KS1; ks++) {
        v8bf a[4];
        #pragma unroll
        for (int mi = 0; mi < 4; mi++)
            a[mi] = __builtin_bit_cast(v8bf,
                *(const uint4*)&xe[(wv * 64 + mi * 16 + lr) * P + ks * 32 + q * 8]);
        v8bf b[NT1];
        #pragma unroll
        for (int nt = 0; nt < NT1; nt++)
            b[nt] = __builtin_bit_cast(v8bf,
                *(const uint4*)(EW1 + (size_t)(nt * 16 + lr) * TDP + ks * 32 + q * 8));
        #pragma unroll
        for (int mi = 0; mi < 4; mi++)
            #pragma unroll
            for (int nt = 0; nt < NT1; nt++)
                acc1[mi][nt] = __builtin_amdgcn_mfma_f32_16x16x32_bf16(a[mi], b[nt], acc1[mi][nt], 0, 0, 0);
    }
    #pragma unroll
    for (int nt = 0; nt < NT1; nt++) {
        const float bias = b1g[nt * 16 + lr];
        #pragma unroll
        for (int mi = 0; mi < 4; mi++) {
            #pragma unroll
            for (int m = 0; m < 4; m++) {
                int row = wv * 64 + mi * 16 + q * 4 + m;
                xe[row * P + nt * 16 + lr] =
                    __float2bfloat16(fmaxf(acc1[mi][nt][m] + bias, 0.f));
            }
        }
    }

    v4f acc2[4][NT2];
    #pragma unroll
    for (int mi = 0; mi < 4; mi++)
        #pragma unroll
        for (int nt = 0; nt < NT2; nt++) acc2[mi][nt] = (v4f){0.f, 0.f, 0.f, 0.f};

    #pragma unroll
    for (int ks = 0; ks < KS2; ks++) {
        v8bf a[4];
        #pragma unroll
        for (int mi = 0; mi < 4; mi++)
            a[mi] = __builtin_bit_cast(v8bf,
                *(const uint4*)&xe[(wv * 64 + mi * 16 + lr) * P + ks * 32 + q * 8]);
        v8bf b[NT2];
        #pragma unroll
        for (int nt = 0; nt < NT2; nt++)
            b[nt] = __builtin_bit_cast(v8bf,
                *(const uint4*)(EW2 + (size_t)(nt * 16 + lr) * H + ks * 32 + q * 8));
        #pragma unroll
        for (int mi = 0; mi < 4; mi++)
            #pragma unroll
            for (int nt = 0; nt < NT2; nt++)
                acc2[mi][nt] = __builtin_amdgcn_mfma_f32_16x16x32_bf16(a[mi], b[nt], acc2[mi][nt], 0, 0, 0);
    }
    #pragma unroll
    for (int mi = 0; mi < 4; mi++) {
        const int p = p0 + (wv * 4 + mi) * 4 + q;
        float vs[NT2];
        float ss = 0.f;
        #pragma unroll
        for (int nt = 0; nt < NT2; nt++) {
            const int c = nt * 16 + lr;
            float v = fmaxf(fmaxf(acc2[mi][nt][0], acc2[mi][nt][1]),
                            fmaxf(acc2[mi][nt][2], acc2[mi][nt][3])) + b2g[c];
            vs[nt] = v;
            if constexpr (sizeof(OT) == 4) out[(size_t)p * C + c] = v;
            else                           out[(size_t)p * C + c] = __float2bfloat16(v);
            if constexpr (PACK) ss = fmaf(v, v, ss);
        }
        if constexpr (PACK) {
            ss += __shfl_xor(ss, 1);
            ss += __shfl_xor(ss, 2);
            ss += __shfl_xor(ss, 4);
            ss += __shfl_xor(ss, 8);
            #pragma unroll
            for (int nt = 0; nt < NT2; nt++) {
                float v = vs[nt];
                __hip_bfloat16 hb = __float2bfloat16(v);
                float hf = __bfloat162float(hb);
                __hip_bfloat16 lb = __float2bfloat16(v - hf);
                xhw[(size_t)p * 32 + nt * 16 + lr] = hb;
                xlw[(size_t)p * 32 + nt * 16 + lr] = lb;
            }
            if (lr == 0) sqw[p] = ss;
        }
    }
}

// ---------------------------------------------------------------------------
// Weight prep (unchanged)
// ---------------------------------------------------------------------------
__global__ void prep_kernel(const float* __restrict__ mW1, const float* __restrict__ mW2,
                            const float* __restrict__ mW3,
                            const float* __restrict__ mb1, const float* __restrict__ mb2,
                            const float* __restrict__ mb3,
                            const float* __restrict__ c1W1, const float* __restrict__ c1W2,
                            const float* __restrict__ c2W1, const float* __restrict__ c2W2,
                            const float* __restrict__ c3W1, const float* __restrict__ c3W2,
                            __hip_bfloat16* __restrict__ WT1, __hip_bfloat16* __restrict__ WT2,
                            __hip_bfloat16* __restrict__ WT3, float* __restrict__ bp,
                            __hip_bfloat16* __restrict__ E11, __hip_bfloat16* __restrict__ E12,
                            __hip_bfloat16* __restrict__ E13,
                            __hip_bfloat16* __restrict__ E21, __hip_bfloat16* __restrict__ E22,
                            __hip_bfloat16* __restrict__ E23)
{
    const int t0 = blockIdx.x * blockDim.x + threadIdx.x;
    const int NT = gridDim.x * blockDim.x;
    for (int i = t0; i < 272 * 136; i += NT) {
        int n = i / 136, k = i - n * 136;
        WT1[i] = (n < 264 && k < 128) ? __float2bfloat16(mW1[(size_t)k * 264 + n]) : __float2bfloat16(0.f);
    }
    for (int i = t0; i < 272 * 296; i += NT) {
        int n = i / 296, k = i - n * 296;
        WT2[i] = (n < 264 && k < 264) ? __float2bfloat16(mW2[(size_t)k * 264 + n]) : __float2bfloat16(0.f);
        WT3[i] = (n < 264 && k < 264) ? __float2bfloat16(mW3[(size_t)k * 264 + n]) : __float2bfloat16(0.f);
    }
    for (int i = t0; i < 3 * 272; i += NT) {
        int l = i / 272, n = i - l * 272;
        const float* bsrc = (l == 0) ? mb1 : (l == 1) ? mb2 : mb3;
        bp[i] = (n < 264) ? bsrc[n] : 0.f;
    }
    for (int i = t0; i < 32 * 32; i += NT) {
        int h = i >> 5, k = i & 31;
        float v = (k == 0) ? (c1W1[h] - c1W1[32 + h]) : (k == 16 ? c1W1[32 + h] : 0.f);
        E11[i] = __float2bfloat16(v);
    }
    for (int i = t0; i < 32 * 64; i += NT) {
        int h = i >> 6, k = i & 63;
        float v = (k < 32) ? (c2W1[k * 32 + h] - c2W1[(k + 32) * 32 + h]) : c2W1[k * 32 + h];
        E12[i] = __float2bfloat16(v);
    }
    for (int i = t0; i < 64 * 64; i += NT) {
        int h = i >> 6, k = i & 63;
        float v = (k < 32) ? (c3W1[k * 64 + h] - c3W1[(k + 32) * 64 + h]) : c3W1[k * 64 + h];
        E13[i] = __float2bfloat16(v);
    }
    for (int i = t0; i < 32 * 32; i += NT) {
        int c = i >> 5, h = i & 31;
        E21[i] = __float2bfloat16(c1W2[h * 32 + c]);
        E22[i] = __float2bfloat16(c2W2[h * 32 + c]);
    }
    for (int i = t0; i < 64 * 64; i += NT) {
        int c = i >> 6, h = i & 63;
        E23[i] = __float2bfloat16(c3W2[h * 64 + c]);
    }
}

// ---------------------------------------------------------------------------
// Final MLP v5 (depth-1 prefetch, 8-wave, bound (512,4) — 91-92 us, stable)
// ---------------------------------------------------------------------------
#define ACT_RB 640   // bytes per act row (5*128); logical cols = 320 bf16

template<int NK>
__device__ __forceinline__ void mlp_layer(
    char* actb, const __hip_bfloat16* __restrict__ WT, const int KP,
    const float* __restrict__ bias, const int wv, const int rlane, const int ph)
{
    v4f acc[2][4], acc16;
    #pragma unroll
    for (int i = 0; i < 2; i++)
        #pragma unroll
        for (int rt = 0; rt < 4; rt++) acc[i][rt] = (v4f){0.f, 0.f, 0.f, 0.f};
    acc16 = (v4f){0.f, 0.f, 0.f, 0.f};

    const int sw = (rlane & 7) << 4;
    const __hip_bfloat16* wbase = WT + (size_t)rlane * KP + ph * 8;
    const bool has16 = (wv >= 4);
    const int r16 = ((wv - 4) & 3) * 16 + rlane;   // tile-16 row (waves 4..7)

    v8bf wb[2][2], wb16[2];
    auto loadW = [&](int ks, int buf) {
        wb[buf][0] = __builtin_bit_cast(v8bf,
            *(const uint4*)(wbase + (size_t)wv * 16 * KP + ks * 32));
        wb[buf][1] = __builtin_bit_cast(v8bf,
            *(const uint4*)(wbase + (size_t)(8 + wv) * 16 * KP + ks * 32));
        if (has16)
            wb16[buf] = __builtin_bit_cast(v8bf,
                *(const uint4*)(wbase + (size_t)256 * KP + ks * 32));
    };
    loadW(0, 0);

    #pragma unroll
    for (int ks = 0; ks < NK; ks++) {
        const int cur = ks & 1;
        if (ks + 1 < NK) loadW(ks + 1, cur ^ 1);   // prefetch next K-step weights
        v8bf ab[4], ab16;
        #pragma unroll
        for (int rt = 0; rt < 4; rt++)
            ab[rt] = __builtin_bit_cast(v8bf,
                *(const uint4*)(actb + (rt * 16 + rlane) * ACT_RB + ((ks * 64 + ph * 16) ^ sw)));
        if (has16)
            ab16 = __builtin_bit_cast(v8bf,
                *(const uint4*)(actb + r16 * ACT_RB + ((ks * 64 + ph * 16) ^ sw)));
        #pragma unroll
        for (int i = 0; i < 2; i++)
            #pragma unroll
            for (int rt = 0; rt < 4; rt++)
                acc[i][rt] = __builtin_amdgcn_mfma_f32_16x16x32_bf16(wb[cur][i], ab[rt], acc[i][rt], 0, 0, 0);
        if (has16)
            acc16 = __builtin_amdgcn_mfma_f32_16x16x32_bf16(wb16[cur], ab16, acc16, 0, 0, 0);
    }
    __syncthreads();   // all reads of act done before overwrite

    #pragma unroll
    for (int i = 0; i < 2; i++) {
        const int col0 = (wv + 8 * i) * 16 + ph * 4;
        const float4 bv = *(const float4*)&bias[col0];
        #pragma unroll
        for (int rt = 0; rt < 4; rt++) {
            const int row = rt * 16 + rlane;
            ushort4 pk;
            pk.x = f2bs(fmaxf(acc[i][rt][0] + bv.x, 0.f));
            pk.y = f2bs(fmaxf(acc[i][rt][1] + bv.y, 0.f));
            pk.z = f2bs(fmaxf(acc[i][rt][2] + bv.z, 0.f));
            pk.w = f2bs(fmaxf(acc[i][rt][3] + bv.w, 0.f));
            *(ushort4*)(actb + row * ACT_RB + ((col0 * 2) ^ ((rlane & 7) << 4))) = pk;
        }
    }
    if (has16) {   // n-tile 16 (cols 256..271), row-tile (wv-4)
        const int col0 = 256 + ph * 4;
        const float4 bv = *(const float4*)&bias[col0];
        ushort4 pk;
        pk.x = f2bs(fmaxf(acc16[0] + bv.x, 0.f));
        pk.y = f2bs(fmaxf(acc16[1] + bv.y, 0.f));
        pk.z = f2bs(fmaxf(acc16[2] + bv.z, 0.f));
        pk.w = f2bs(fmaxf(acc16[3] + bv.w, 0.f));
        *(ushort4*)(actb + r16 * ACT_RB + ((col0 * 2) ^ ((rlane & 7) << 4))) = pk;
    }
    __syncthreads();
}

__global__ __launch_bounds__(512, 4)
void mlp_kernel(const float* __restrict__ x1, const float* __restrict__ x2,
                const __hip_bfloat16* __restrict__ x3,
                const __hip_bfloat16* __restrict__ WT1, const __hip_bfloat16* __restrict__ WT2,
                const __hip_bfloat16* __restrict__ WT3, const float* __restrict__ bp,
                const float* __restrict__ mW4, const float* __restrict__ mb4,
                float* __restrict__ outp)
{
    __shared__ __align__(16) char actb[64 * ACT_RB];   // 40960 B, swizzled
    __shared__ __align__(16) float W4s[264 * 2 + 2];
    __shared__ float lsm[512];

    const int tid = threadIdx.x;
    const int wv = tid >> 6, lane = tid & 63;
    const int rlane = lane & 15, ph = lane >> 4;
    const size_t row0 = (size_t)blockIdx.x * 64;

    // --- stage: cols [0,128) = [x1|x2|x3] as bf16; zero pad cols [272,320) ---
    {
        uint4 z; z.x = 0u; z.y = 0u; z.z = 0u; z.w = 0u;
        for (int t = tid; t < 64 * 6; t += 512) {
            int r = t / 6, s = t - r * 6;
            int cb = (34 + s) * 16;                       // bytes 544..639
            *(uint4*)(actb + r * ACT_RB + (cb ^ ((r & 7) << 4))) = z;
        }
        for (int t = tid; t < 64 * 8; t += 512) {
            int r = t >> 3, g = t & 7;
            size_t grow = row0 + r;
            const int swr = (r & 7) << 4;
            float4 fa = *(const float4*)&x1[grow * 32 + g * 4];
            uint2 ua; ua.x = packbf2(fa.x, fa.y); ua.y = packbf2(fa.z, fa.w);
            *(uint2*)(actb + r * ACT_RB + ((g * 8) ^ swr)) = ua;
            float4 fb = *(const float4*)&x2[grow * 32 + g * 4];
            uint2 ub; ub.x = packbf2(fb.x, fb.y); ub.y = packbf2(fb.z, fb.w);
            *(uint2*)(actb + r * ACT_RB + ((64 + g * 8) ^ swr)) = ub;
            uint4 uc = *(const uint4*)&x3[grow * 64 + g * 8];
            *(uint4*)(actb + r * ACT_RB + ((128 + g * 16) ^ swr)) = uc;
        }
        for (int t = tid; t < 530; t += 512) {
            if (t < 528) { int c = t / 264, k2 = t - c * 264; W4s[t] = mW4[(size_t)k2 * 2 + c]; }
            else W4s[t] = mb4[t - 528];
        }
    }
    __syncthreads();

    mlp_layer<4>(actb, WT1, 136, bp,       wv, rlane, ph);
    mlp_layer<9>(actb, WT2, 296, bp + 272, wv, rlane, ph);
    mlp_layer<9>(actb, WT3, 296, bp + 544, wv, rlane, ph);

    {   // final 264->2 dot: 512 threads = 64 rows x 2 cols x 4 k-quarters
        const int r = tid >> 3, rem = tid & 7;
        const int c = rem >> 2, h = rem & 3;
        const float* wp = &W4s[c * 264];
        const int swr = (r & 7) << 4;
        const int k0 = (h == 0) ? 0 : (8 + 64 * h);       // {0,72,136,200}
        const int k1 = k0 + ((h == 0) ? 72 : 64);
        float s = 0.f;
        for (int k = k0; k < k1; k += 8) {
            uint4 u = *(const uint4*)(actb + r * ACT_RB + ((2 * k) ^ swr));
            float4 wa = *(const float4*)&wp[k];
            float4 wb2 = *(const float4*)&wp[k + 4];
            s = fmaf(bflo(u.x), wa.x, s); s = fmaf(bfhi(u.x), wa.y, s);
            s = fmaf(bflo(u.y), wa.z, s); s = fmaf(bfhi(u.y), wa.w, s);
            s = fmaf(bflo(u.z), wb2.x, s); s = fmaf(bfhi(u.z), wb2.y, s);
            s = fmaf(bflo(u.w), wb2.z, s); s = fmaf(bfhi(u.w), wb2.w, s);
        }
        lsm[tid] = s;
    }
    __syncthreads();
    if (tid < 64) {
        float l0 = lsm[tid * 8 + 0] + lsm[tid * 8 + 1] + lsm[tid * 8 + 2] + lsm[tid * 8 + 3] + W4s[528];
        float l1 = lsm[tid * 8 + 4] + lsm[tid * 8 + 5] + lsm[tid * 8 + 6] + lsm[tid * 8 + 7] + W4s[529];
        float m = fmaxf(l0, l1);
        float lse = m + __logf(__expf(l0 - m) + __expf(l1 - m));
        float2 o; o.x = l0 - lse; o.y = l1 - lse;
        *(float2*)&outp[(row0 + tid) * 2] = o;
    }
}

// ---------------------------------------------------------------------------
extern "C" void kernel_launch(void* const* d_in, const int* in_sizes, int n_in,
                              void* d_out, int out_size, void* d_ws, size_t ws_size,
                              hipStream_t stream)
{
    const float* x    = (const float*)d_in[0];
    const float* c1W1 = (const float*)d_in[2];
    const float* c1b1 = (const float*)d_in[3];
    const float* c1W2 = (const float*)d_in[4];
    const float* c1b2 = (const float*)d_in[5];
    const float* c2W1 = (const float*)d_in[6];
    const float* c2b1 = (const float*)d_in[7];
    const float* c2W2 = (const float*)d_in[8];
    const float* c2b2 = (const float*)d_in[9];
    const float* c3W1 = (const float*)d_in[10];
    const float* c3b1 = (const float*)d_in[11];
    const float* c3W2 = (const float*)d_in[12];
    const float* c3b2 = (const float*)d_in[13];
    const float* mW1  = (const float*)d_in[14];
    const float* mb1  = (const float*)d_in[15];
    const float* mW2  = (const float*)d_in[16];
    const float* mb2  = (const float*)d_in[17];
    const float* mW3  = (const float*)d_in[18];
    const float* mb3  = (const float*)d_in[19];
    const float* mW4  = (const float*)d_in[20];
    const float* mb4  = (const float*)d_in[21];

    // workspace carve (~70 MB)
    float* x1 = (float*)d_ws;                                        // [N,32] f32
    float* x2 = x1 + (size_t)NROWS * 32;                             // [N,32] f32
    __hip_bfloat16* x3 = (__hip_bfloat16*)(x2 + (size_t)NROWS * 32); // [N,64] bf16
    int* nidx = (int*)(x3 + (size_t)NROWS * 64);                     // [N,4] i32
    __hip_bfloat16* WT1 = (__hip_bfloat16*)(nidx + (size_t)NROWS * 4);
    __hip_bfloat16* WT2 = WT1 + 272 * 136;
    __hip_bfloat16* WT3 = WT2 + 272 * 296;
    float* bp = (float*)(WT3 + 272 * 296);                           // [3][272] f32
    __hip_bfloat16* xph = (__hip_bfloat16*)(bp + 3 * 272);           // [N,32] bf16
    __hip_bfloat16* xpl = xph + (size_t)NROWS * 32;                  // [N,32] bf16
    float* sqw = (float*)(xpl + (size_t)NROWS * 32);                 // [N] f32
    __hip_bfloat16* E11 = (__hip_bfloat16*)(sqw + NROWS);            // [32][32]
    __hip_bfloat16* E12 = E11 + 32 * 32;                             // [32][64]
    __hip_bfloat16* E13 = E12 + 32 * 64;                             // [64][64]
    __hip_bfloat16* E21 = E13 + 64 * 64;                             // [32][32]
    __hip_bfloat16* E22 = E21 + 32 * 32;                             // [32][32]
    __hip_bfloat16* E23 = E22 + 32 * 32;                             // [64][64]

    prep_kernel<<<dim3(512), 256, 0, stream>>>(mW1, mW2, mW3, mb1, mb2, mb3,
                                               c1W1, c1W2, c2W1, c2W2, c3W1, c3W2,
                                               WT1, WT2, WT3, bp,
                                               E11, E12, E13, E21, E22, E23);

    dim3 kgrid(PP / 64, BB);
    dim3 pgrid(NROWS * 4 / 256);
    dim3 egrid(NROWS / 64);

    pack_kernel<<<pgrid, 256, 0, stream>>>(x, 1, xph, xpl, sqw);
    knn_mfma<<<kgrid, 256, 0, stream>>>(xph, xpl, sqw, nidx);
    edge_mfma<1, 32, 32, float, true><<<egrid, 256, 0, stream>>>(
        x, nidx, E11, E21, c1b1, c1b2, x1, xph, xpl, sqw);

    knn_mfma<<<kgrid, 256, 0, stream>>>(xph, xpl, sqw, nidx);
    edge_mfma<32, 32, 32, float, true><<<egrid, 256, 0, stream>>>(
        x1, nidx, E12, E22, c2b1, c2b2, x2, xph, xpl, sqw);

    knn_mfma<<<kgrid, 256, 0, stream>>>(xph, xpl, sqw, nidx);
    edge_mfma<32, 64, 64, __hip_bfloat16, false><<<egrid, 256, 0, stream>>>(
        x2, nidx, E13, E23, c3b1, c3b2, x3, nullptr, nullptr, nullptr);

    mlp_kernel<<<dim3(NROWS / 64), 512, 0, stream>>>(x1, x2, x3, WT1, WT2, WT3, bp,
                                                     mW4, mb4, (float*)d_out);
}

// Round 16
// 389.175 us; speedup vs baseline: 1.0533x; 1.0533x over previous
//
#include <hip/hip_runtime.h>
#include <hip/hip_bf16.h>
#include <float.h>
#include <math.h>

#define BB 128
#define PP 1024
#define KNN 4
#define NROWS (BB * PP)

typedef __bf16 v8bf __attribute__((ext_vector_type(8)));
typedef float  v4f  __attribute__((ext_vector_type(4)));

__device__ inline unsigned short f2bs(float f) {
    __hip_bfloat16 h = __float2bfloat16(f);
    return *(unsigned short*)&h;
}
__device__ inline unsigned packbf2(float a, float b) {
    return (unsigned)f2bs(a) | ((unsigned)f2bs(b) << 16);
}
// bf16 pair (packed in u32) -> two f32, bit-exact
__device__ inline float bflo(unsigned u) { return __builtin_bit_cast(float, u << 16); }
__device__ inline float bfhi(unsigned u) { return __builtin_bit_cast(float, u & 0xFFFF0000u); }

// sorted-4 insert helper: median-of-3 (single VOP3 on gfx950)
__device__ inline unsigned med3u(unsigned a, unsigned b, unsigned c) {
    unsigned d;
    asm("v_med3_u32 %0, %1, %2, %3" : "=v"(d) : "v"(a), "v"(b), "v"(c));
    return d;
}

// ---------------------------------------------------------------------------
// Pack kernel (raw input x only; layers 2/3 pack fused into edge_mfma)
// ---------------------------------------------------------------------------
__global__ __launch_bounds__(256)
void pack_kernel(const float* __restrict__ src, int D,
                 __hip_bfloat16* __restrict__ xh, __hip_bfloat16* __restrict__ xl,
                 float* __restrict__ sq)
{
    const int t = blockIdx.x * 256 + threadIdx.x;     // t < NROWS*4
    const int row = t >> 2, part = t & 3;
    float v[8];
    #pragma unroll
    for (int u = 0; u < 8; u++) {
        int d = part * 8 + u;
        v[u] = (d < D) ? src[(size_t)row * D + d] : 0.f;
    }
    float s = 0.f;
    unsigned int hw[4], lw[4];
    #pragma unroll
    for (int w = 0; w < 4; w++) {
        unsigned short h2[2], l2[2];
        #pragma unroll
        for (int e = 0; e < 2; e++) {
            float x = v[2 * w + e];
            __hip_bfloat16 hb = __float2bfloat16(x);
            float hf = __bfloat162float(hb);
            __hip_bfloat16 lb = __float2bfloat16(x - hf);
            h2[e] = *(unsigned short*)&hb;
            l2[e] = *(unsigned short*)&lb;
            s = fmaf(x, x, s);
        }
        hw[w] = (unsigned int)h2[0] | ((unsigned int)h2[1] << 16);
        lw[w] = (unsigned int)l2[0] | ((unsigned int)l2[1] << 16);
    }
    s += __shfl_xor(s, 1);
    s += __shfl_xor(s, 2);
    uint4 hv; hv.x = hw[0]; hv.y = hw[1]; hv.z = hw[2]; hv.w = hw[3];
    uint4 lv; lv.x = lw[0]; lv.y = lw[1]; lv.z = lw[2]; lv.w = lw[3];
    *(uint4*)&xh[(size_t)row * 32 + part * 8] = hv;
    *(uint4*)&xl[(size_t)row * 32 + part * 8] = lv;
    if (part == 0) sq[row] = s;
}

// ---------------------------------------------------------------------------
// MFMA kNN v11 (FINAL: best measured knn at 391us total). Swapped-operand
// mfma(cand,query): query in lane dim, candidates in register rows -> top-4
// fully in-register; butterfly shfl merge; 4KB cross-wave dump. v12's
// 2-query/2-cand wave split regressed (-19us: shorter independent MFMA
// streams exposed the med3 chain latency); v9/v12 occupancy pushes both
// failed -> this is the measured optimum of the family.
// ---------------------------------------------------------------------------
__global__ __launch_bounds__(256, 4)
void knn_mfma(const __hip_bfloat16* __restrict__ xh, const __hip_bfloat16* __restrict__ xl,
              const float* __restrict__ sq, int* __restrict__ nidx)
{
    __shared__ unsigned cand[16 * 64];                // 4 KiB

    const int tid = threadIdx.x;
    const int wv = tid >> 6, lane = tid & 63;
    const int lr = lane & 15, lq = lane >> 4;
    const int b = blockIdx.y, i0 = blockIdx.x * 64;
    const size_t Rb = (size_t)b * PP;

    // query fragments (B operand): thread's queries are it*16+lr
    v8bf qh[4], ql[4];
    #pragma unroll
    for (int it = 0; it < 4; it++) {
        size_t g = Rb + i0 + it * 16 + lr;
        qh[it] = __builtin_bit_cast(v8bf, *(const uint4*)(xh + g * 32 + lq * 8));
        ql[it] = __builtin_bit_cast(v8bf, *(const uint4*)(xl + g * 32 + lq * 8));
    }
    float sqq[4];
    #pragma unroll
    for (int it = 0; it < 4; it++)
        sqq[it] = sq[Rb + i0 + it * 16 + lr];

    unsigned mn[4][4];                                // per-query sorted top-4
    #pragma unroll
    for (int it = 0; it < 4; it++)
        #pragma unroll
        for (int s = 0; s < 4; s++) mn[it][s] = ~0u;

    for (int ch = 0; ch < 8; ch++) {
        #pragma unroll
        for (int jt2 = 0; jt2 < 2; jt2++) {
            const int jt = ch * 128 + (wv * 2 + jt2) * 16;   // candidate tile base
            const size_t gj = Rb + jt + lr;                   // A-frag row
            v8bf bh = __builtin_bit_cast(v8bf, *(const uint4*)(xh + gj * 32 + lq * 8));
            v8bf bl = __builtin_bit_cast(v8bf, *(const uint4*)(xl + gj * 32 + lq * 8));
            float4 sqc = *(const float4*)&sq[Rb + jt + lq * 4];  // this thread's 4 cands
            const float sqcv[4] = {sqc.x, sqc.y, sqc.z, sqc.w};
            #pragma unroll
            for (int it = 0; it < 4; it++) {
                v4f a = (v4f){0.f, 0.f, 0.f, 0.f};
                a = __builtin_amdgcn_mfma_f32_16x16x32_bf16(bl, ql[it], a, 0, 0, 0);
                a = __builtin_amdgcn_mfma_f32_16x16x32_bf16(bl, qh[it], a, 0, 0, 0);
                a = __builtin_amdgcn_mfma_f32_16x16x32_bf16(bh, ql[it], a, 0, 0, 0);
                a = __builtin_amdgcn_mfma_f32_16x16x32_bf16(bh, qh[it], a, 0, 0, 0);
                #pragma unroll
                for (int m = 0; m < 4; m++) {
                    float s = fmaf(-2.f, a[m], sqq[it] + sqcv[m]);  // ||xi-xj||^2
                    s = fmaxf(s, 0.f);
                    unsigned k = (__builtin_bit_cast(unsigned, s) & 0xFFFFFC00u)
                                 | (unsigned)(jt + lq * 4 + m);
                    unsigned n0 = min(mn[it][0], k);
                    unsigned n1 = med3u(mn[it][0], mn[it][1], k);
                    unsigned n2 = med3u(mn[it][1], mn[it][2], k);
                    unsigned n3 = med3u(mn[it][2], mn[it][3], k);
                    mn[it][0] = n0; mn[it][1] = n1; mn[it][2] = n2; mn[it][3] = n3;
                }
            }
        }
    }

    // intra-wave merge across lq (lanes l, l^16, l^32): butterfly; all lanes
    // end with the wave's top-4 per query.
    #pragma unroll
    for (int d = 16; d <= 32; d <<= 1) {
        #pragma unroll
        for (int it = 0; it < 4; it++) {
            unsigned o0 = __shfl_xor(mn[it][0], d);
            unsigned o1 = __shfl_xor(mn[it][1], d);
            unsigned o2 = __shfl_xor(mn[it][2], d);
            unsigned o3 = __shfl_xor(mn[it][3], d);
            #pragma unroll
            for (int e = 0; e < 4; e++) {
                unsigned k = (e == 0) ? o0 : (e == 1) ? o1 : (e == 2) ? o2 : o3;
                unsigned n0 = min(mn[it][0], k);
                unsigned n1 = med3u(mn[it][0], mn[it][1], k);
                unsigned n2 = med3u(mn[it][1], mn[it][2], k);
                unsigned n3 = med3u(mn[it][2], mn[it][3], k);
                mn[it][0] = n0; mn[it][1] = n1; mn[it][2] = n2; mn[it][3] = n3;
            }
        }
    }

    // cross-wave dump: 4 waves x 4 slots per query
    if (lane < 16) {
        #pragma unroll
        for (int it = 0; it < 4; it++)
            #pragma unroll
            for (int s = 0; s < 4; s++)
                cand[(wv * 4 + s) * 64 + it * 16 + lr] = mn[it][s];
    }
    __syncthreads();

    if (tid < 64) {
        unsigned g0 = ~0u, g1 = ~0u, g2 = ~0u, g3 = ~0u;
        #pragma unroll
        for (int s2 = 0; s2 < 16; s2++) {
            unsigned k = cand[s2 * 64 + tid];
            unsigned n0 = min(g0, k);
            unsigned n1 = med3u(g0, g1, k);
            unsigned n2 = med3u(g1, g2, k);
            unsigned n3 = med3u(g2, g3, k);
            g0 = n0; g1 = n1; g2 = n2; g3 = n3;
        }
        const int base = (int)Rb;
        int* op = nidx + (size_t)(Rb + i0 + tid) * KNN;
        op[0] = base + (int)(g0 & 1023u);
        op[1] = base + (int)(g1 & 1023u);
        op[2] = base + (int)(g2 & 1023u);
        op[3] = base + (int)(g3 & 1023u);
    }
}

// ---------------------------------------------------------------------------
// Edge-MLP v4 (pack fusion)
// ---------------------------------------------------------------------------
template<int D, int H, int C, typename OT, bool PACK>
__global__ __launch_bounds__(256, 4)
void edge_mfma(const float* __restrict__ x, const int* __restrict__ nidx,
               const __hip_bfloat16* __restrict__ EW1, const __hip_bfloat16* __restrict__ EW2,
               const float* __restrict__ b1g, const float* __restrict__ b2g,
               OT* __restrict__ out,
               __hip_bfloat16* __restrict__ xhw, __hip_bfloat16* __restrict__ xlw,
               float* __restrict__ sqw)
{
    constexpr int NE = 256;
    constexpr int TDP = (D == 1) ? 32 : 64;
    constexpr int DP  = TDP / 2;
    constexpr int P   = ((TDP > H) ? TDP : H) + 8;
    constexpr int NT1 = H / 16, NT2 = C / 16;
    constexpr int KS1 = TDP / 32, KS2 = H / 32;

    __shared__ __hip_bfloat16 xe[NE * P];

    const int tid = threadIdx.x;
    const int wv = tid >> 6, lane = tid & 63;
    const int lr = lane & 15, q = lane >> 4;
    const int p0 = blockIdx.x * 64;

    {
        const int e = wv * 64 + lane;
        const int j = nidx[(size_t)p0 * KNN + e];
        const int pi = p0 + (e >> 2);
        if constexpr (D == 1) {
            #pragma unroll
            for (int s = 0; s < P / 8; s++) {
                uint4 z; z.x = 0u; z.y = 0u; z.z = 0u; z.w = 0u;
                *(uint4*)&xe[e * P + s * 8] = z;
            }
            xe[e * P + 0]  = __float2bfloat16(x[pi]);
            xe[e * P + DP] = __float2bfloat16(x[j]);
        } else {
            const float* si = x + (size_t)pi * D;
            const float* sj = x + (size_t)j * D;
            #pragma unroll
            for (int s = 0; s < D / 8; s++) {
                float4 f0 = *(const float4*)&si[s * 8];
                float4 f1 = *(const float4*)&si[s * 8 + 4];
                uint4 uv;
                uv.x = packbf2(f0.x, f0.y); uv.y = packbf2(f0.z, f0.w);
                uv.z = packbf2(f1.x, f1.y); uv.w = packbf2(f1.z, f1.w);
                *(uint4*)&xe[e * P + s * 8] = uv;
            }
            #pragma unroll
            for (int s = 0; s < D / 8; s++) {
                float4 f0 = *(const float4*)&sj[s * 8];
                float4 f1 = *(const float4*)&sj[s * 8 + 4];
                uint4 uv;
                uv.x = packbf2(f0.x, f0.y); uv.y = packbf2(f0.z, f0.w);
                uv.z = packbf2(f1.x, f1.y); uv.w = packbf2(f1.z, f1.w);
                *(uint4*)&xe[e * P + DP + s * 8] = uv;
            }
        }
    }

    v4f acc1[4][NT1];
    #pragma unroll
    for (int mi = 0; mi < 4; mi++)
        #pragma unroll
        for (int nt = 0; nt < NT1; nt++) acc1[mi][nt] = (v4f){0.f, 0.f, 0.f, 0.f};

    #pragma unroll
    for (int ks = 0; ks < KS1; ks++) {
        v8bf a[4];
        #pragma unroll
        for (int mi = 0; mi < 4; mi++)
            a[mi] = __builtin_bit_cast(v8bf,
                *(const uint4*)&xe[(wv * 64 + mi * 16 + lr) * P + ks * 32 + q * 8]);
        v8bf b[NT1];
        #pragma unroll
        for (int nt = 0; nt < NT1; nt++)
            b[nt] = __builtin_bit_cast(v8bf,
                *(const uint4*)(EW1 + (size_t)(nt * 16 + lr) * TDP + ks * 32 + q * 8));
        #pragma unroll
        for (int mi = 0; mi < 4; mi++)
            #pragma unroll
            for (int nt = 0; nt < NT1; nt++)
                acc1[mi][nt] = __builtin_amdgcn_mfma_f32_16x16x32_bf16(a[mi], b[nt], acc1[mi][nt], 0, 0, 0);
    }
    #pragma unroll
    for (int nt = 0; nt < NT1; nt++) {
        const float bias = b1g[nt * 16 + lr];
        #pragma unroll
        for (int mi = 0; mi < 4; mi++) {
            #pragma unroll
            for (int m = 0; m < 4; m++) {
                int row = wv * 64 + mi * 16 + q * 4 + m;
                xe[row * P + nt * 16 + lr] =
                    __float2bfloat16(fmaxf(acc1[mi][nt][m] + bias, 0.f));
            }
        }
    }

    v4f acc2[4][NT2];
    #pragma unroll
    for (int mi = 0; mi < 4; mi++)
        #pragma unroll
        for (int nt = 0; nt < NT2; nt++) acc2[mi][nt] = (v4f){0.f, 0.f, 0.f, 0.f};

    #pragma unroll
    for (int ks = 0; ks < KS2; ks++) {
        v8bf a[4];
        #pragma unroll
        for (int mi = 0; mi < 4; mi++)
            a[mi] = __builtin_bit_cast(v8bf,
                *(const uint4*)&xe[(wv * 64 + mi * 16 + lr) * P + ks * 32 + q * 8]);
        v8bf b[NT2];
        #pragma unroll
        for (int nt = 0; nt < NT2; nt++)
            b[nt] = __builtin_bit_cast(v8bf,
                *(const uint4*)(EW2 + (size_t)(nt * 16 + lr) * H + ks * 32 + q * 8));
        #pragma unroll
        for (int mi = 0; mi < 4; mi++)
            #pragma unroll
            for (int nt = 0; nt < NT2; nt++)
                acc2[mi][nt] = __builtin_amdgcn_mfma_f32_16x16x32_bf16(a[mi], b[nt], acc2[mi][nt], 0, 0, 0);
    }
    #pragma unroll
    for (int mi = 0; mi < 4; mi++) {
        const int p = p0 + (wv * 4 + mi) * 4 + q;
        float vs[NT2];
        float ss = 0.f;
        #pragma unroll
        for (int nt = 0; nt < NT2; nt++) {
            const int c = nt * 16 + lr;
            float v = fmaxf(fmaxf(acc2[mi][nt][0], acc2[mi][nt][1]),
                            fmaxf(acc2[mi][nt][2], acc2[mi][nt][3])) + b2g[c];
            vs[nt] = v;
            if constexpr (sizeof(OT) == 4) out[(size_t)p * C + c] = v;
            else                           out[(size_t)p * C + c] = __float2bfloat16(v);
            if constexpr (PACK) ss = fmaf(v, v, ss);
        }
        if constexpr (PACK) {
            ss += __shfl_xor(ss, 1);
            ss += __shfl_xor(ss, 2);
            ss += __shfl_xor(ss, 4);
            ss += __shfl_xor(ss, 8);
            #pragma unroll
            for (int nt = 0; nt < NT2; nt++) {
                float v = vs[nt];
                __hip_bfloat16 hb = __float2bfloat16(v);
                float hf = __bfloat162float(hb);
                __hip_bfloat16 lb = __float2bfloat16(v - hf);
                xhw[(size_t)p * 32 + nt * 16 + lr] = hb;
                xlw[(size_t)p * 32 + nt * 16 + lr] = lb;
            }
            if (lr == 0) sqw[p] = ss;
        }
    }
}

// ---------------------------------------------------------------------------
// Weight prep (unchanged)
// ---------------------------------------------------------------------------
__global__ void prep_kernel(const float* __restrict__ mW1, const float* __restrict__ mW2,
                            const float* __restrict__ mW3,
                            const float* __restrict__ mb1, const float* __restrict__ mb2,
                            const float* __restrict__ mb3,
                            const float* __restrict__ c1W1, const float* __restrict__ c1W2,
                            const float* __restrict__ c2W1, const float* __restrict__ c2W2,
                            const float* __restrict__ c3W1, const float* __restrict__ c3W2,
                            __hip_bfloat16* __restrict__ WT1, __hip_bfloat16* __restrict__ WT2,
                            __hip_bfloat16* __restrict__ WT3, float* __restrict__ bp,
                            __hip_bfloat16* __restrict__ E11, __hip_bfloat16* __restrict__ E12,
                            __hip_bfloat16* __restrict__ E13,
                            __hip_bfloat16* __restrict__ E21, __hip_bfloat16* __restrict__ E22,
                            __hip_bfloat16* __restrict__ E23)
{
    const int t0 = blockIdx.x * blockDim.x + threadIdx.x;
    const int NT = gridDim.x * blockDim.x;
    for (int i = t0; i < 272 * 136; i += NT) {
        int n = i / 136, k = i - n * 136;
        WT1[i] = (n < 264 && k < 128) ? __float2bfloat16(mW1[(size_t)k * 264 + n]) : __float2bfloat16(0.f);
    }
    for (int i = t0; i < 272 * 296; i += NT) {
        int n = i / 296, k = i - n * 296;
        WT2[i] = (n < 264 && k < 264) ? __float2bfloat16(mW2[(size_t)k * 264 + n]) : __float2bfloat16(0.f);
        WT3[i] = (n < 264 && k < 264) ? __float2bfloat16(mW3[(size_t)k * 264 + n]) : __float2bfloat16(0.f);
    }
    for (int i = t0; i < 3 * 272; i += NT) {
        int l = i / 272, n = i - l * 272;
        const float* bsrc = (l == 0) ? mb1 : (l == 1) ? mb2 : mb3;
        bp[i] = (n < 264) ? bsrc[n] : 0.f;
    }
    for (int i = t0; i < 32 * 32; i += NT) {
        int h = i >> 5, k = i & 31;
        float v = (k == 0) ? (c1W1[h] - c1W1[32 + h]) : (k == 16 ? c1W1[32 + h] : 0.f);
        E11[i] = __float2bfloat16(v);
    }
    for (int i = t0; i < 32 * 64; i += NT) {
        int h = i >> 6, k = i & 63;
        float v = (k < 32) ? (c2W1[k * 32 + h] - c2W1[(k + 32) * 32 + h]) : c2W1[k * 32 + h];
        E12[i] = __float2bfloat16(v);
    }
    for (int i = t0; i < 64 * 64; i += NT) {
        int h = i >> 6, k = i & 63;
        float v = (k < 32) ? (c3W1[k * 64 + h] - c3W1[(k + 32) * 64 + h]) : c3W1[k * 64 + h];
        E13[i] = __float2bfloat16(v);
    }
    for (int i = t0; i < 32 * 32; i += NT) {
        int c = i >> 5, h = i & 31;
        E21[i] = __float2bfloat16(c1W2[h * 32 + c]);
        E22[i] = __float2bfloat16(c2W2[h * 32 + c]);
    }
    for (int i = t0; i < 64 * 64; i += NT) {
        int c = i >> 6, h = i & 63;
        E23[i] = __float2bfloat16(c3W2[h * 64 + c]);
    }
}

// ---------------------------------------------------------------------------
// Final MLP v5 (depth-1 prefetch, 8-wave, bound (512,4) — 91 us, stable)
// ---------------------------------------------------------------------------
#define ACT_RB 640   // bytes per act row (5*128); logical cols = 320 bf16

template<int NK>
__device__ __forceinline__ void mlp_layer(
    char* actb, const __hip_bfloat16* __restrict__ WT, const int KP,
    const float* __restrict__ bias, const int wv, const int rlane, const int ph)
{
    v4f acc[2][4], acc16;
    #pragma unroll
    for (int i = 0; i < 2; i++)
        #pragma unroll
        for (int rt = 0; rt < 4; rt++) acc[i][rt] = (v4f){0.f, 0.f, 0.f, 0.f};
    acc16 = (v4f){0.f, 0.f, 0.f, 0.f};

    const int sw = (rlane & 7) << 4;
    const __hip_bfloat16* wbase = WT + (size_t)rlane * KP + ph * 8;
    const bool has16 = (wv >= 4);
    const int r16 = ((wv - 4) & 3) * 16 + rlane;   // tile-16 row (waves 4..7)

    v8bf wb[2][2], wb16[2];
    auto loadW = [&](int ks, int buf) {
        wb[buf][0] = __builtin_bit_cast(v8bf,
            *(const uint4*)(wbase + (size_t)wv * 16 * KP + ks * 32));
        wb[buf][1] = __builtin_bit_cast(v8bf,
            *(const uint4*)(wbase + (size_t)(8 + wv) * 16 * KP + ks * 32));
        if (has16)
            wb16[buf] = __builtin_bit_cast(v8bf,
                *(const uint4*)(wbase + (size_t)256 * KP + ks * 32));
    };
    loadW(0, 0);

    #pragma unroll
    for (int ks = 0; ks < NK; ks++) {
        const int cur = ks & 1;
        if (ks + 1 < NK) loadW(ks + 1, cur ^ 1);   // prefetch next K-step weights
        v8bf ab[4], ab16;
        #pragma unroll
        for (int rt = 0; rt < 4; rt++)
            ab[rt] = __builtin_bit_cast(v8bf,
                *(const uint4*)(actb + (rt * 16 + rlane) * ACT_RB + ((ks * 64 + ph * 16) ^ sw)));
        if (has16)
            ab16 = __builtin_bit_cast(v8bf,
                *(const uint4*)(actb + r16 * ACT_RB + ((ks * 64 + ph * 16) ^ sw)));
        #pragma unroll
        for (int i = 0; i < 2; i++)
            #pragma unroll
            for (int rt = 0; rt < 4; rt++)
                acc[i][rt] = __builtin_amdgcn_mfma_f32_16x16x32_bf16(wb[cur][i], ab[rt], acc[i][rt], 0, 0, 0);
        if (has16)
            acc16 = __builtin_amdgcn_mfma_f32_16x16x32_bf16(wb16[cur], ab16, acc16, 0, 0, 0);
    }
    __syncthreads();   // all reads of act done before overwrite

    #pragma unroll
    for (int i = 0; i < 2; i++) {
        const int col0 = (wv + 8 * i) * 16 + ph * 4;
        const float4 bv = *(const float4*)&bias[col0];
        #pragma unroll
        for (int rt = 0; rt < 4; rt++) {
            const int row = rt * 16 + rlane;
            ushort4 pk;
            pk.x = f2bs(fmaxf(acc[i][rt][0] + bv.x, 0.f));
            pk.y = f2bs(fmaxf(acc[i][rt][1] + bv.y, 0.f));
            pk.z = f2bs(fmaxf(acc[i][rt][2] + bv.z, 0.f));
            pk.w = f2bs(fmaxf(acc[i][rt][3] + bv.w, 0.f));
            *(ushort4*)(actb + row * ACT_RB + ((col0 * 2) ^ ((rlane & 7) << 4))) = pk;
        }
    }
    if (has16) {   // n-tile 16 (cols 256..271), row-tile (wv-4)
        const int col0 = 256 + ph * 4;
        const float4 bv = *(const float4*)&bias[col0];
        ushort4 pk;
        pk.x = f2bs(fmaxf(acc16[0] + bv.x, 0.f));
        pk.y = f2bs(fmaxf(acc16[1] + bv.y, 0.f));
        pk.z = f2bs(fmaxf(acc16[2] + bv.z, 0.f));
        pk.w = f2bs(fmaxf(acc16[3] + bv.w, 0.f));
        *(ushort4*)(actb + r16 * ACT_RB + ((col0 * 2) ^ ((rlane & 7) << 4))) = pk;
    }
    __syncthreads();
}

__global__ __launch_bounds__(512, 4)
void mlp_kernel(const float* __restrict__ x1, const float* __restrict__ x2,
                const __hip_bfloat16* __restrict__ x3,
                const __hip_bfloat16* __restrict__ WT1, const __hip_bfloat16* __restrict__ WT2,
                const __hip_bfloat16* __restrict__ WT3, const float* __restrict__ bp,
                const float* __restrict__ mW4, const float* __restrict__ mb4,
                float* __restrict__ outp)
{
    __shared__ __align__(16) char actb[64 * ACT_RB];   // 40960 B, swizzled
    __shared__ __align__(16) float W4s[264 * 2 + 2];
    __shared__ float lsm[512];

    const int tid = threadIdx.x;
    const int wv = tid >> 6, lane = tid & 63;
    const int rlane = lane & 15, ph = lane >> 4;
    const size_t row0 = (size_t)blockIdx.x * 64;

    // --- stage: cols [0,128) = [x1|x2|x3] as bf16; zero pad cols [272,320) ---
    {
        uint4 z; z.x = 0u; z.y = 0u; z.z = 0u; z.w = 0u;
        for (int t = tid; t < 64 * 6; t += 512) {
            int r = t / 6, s = t - r * 6;
            int cb = (34 + s) * 16;                       // bytes 544..639
            *(uint4*)(actb + r * ACT_RB + (cb ^ ((r & 7) << 4))) = z;
        }
        for (int t = tid; t < 64 * 8; t += 512) {
            int r = t >> 3, g = t & 7;
            size_t grow = row0 + r;
            const int swr = (r & 7) << 4;
            float4 fa = *(const float4*)&x1[grow * 32 + g * 4];
            uint2 ua; ua.x = packbf2(fa.x, fa.y); ua.y = packbf2(fa.z, fa.w);
            *(uint2*)(actb + r * ACT_RB + ((g * 8) ^ swr)) = ua;
            float4 fb = *(const float4*)&x2[grow * 32 + g * 4];
            uint2 ub; ub.x = packbf2(fb.x, fb.y); ub.y = packbf2(fb.z, fb.w);
            *(uint2*)(actb + r * ACT_RB + ((64 + g * 8) ^ swr)) = ub;
            uint4 uc = *(const uint4*)&x3[grow * 64 + g * 8];
            *(uint4*)(actb + r * ACT_RB + ((128 + g * 16) ^ swr)) = uc;
        }
        for (int t = tid; t < 530; t += 512) {
            if (t < 528) { int c = t / 264, k2 = t - c * 264; W4s[t] = mW4[(size_t)k2 * 2 + c]; }
            else W4s[t] = mb4[t - 528];
        }
    }
    __syncthreads();

    mlp_layer<4>(actb, WT1, 136, bp,       wv, rlane, ph);
    mlp_layer<9>(actb, WT2, 296, bp + 272, wv, rlane, ph);
    mlp_layer<9>(actb, WT3, 296, bp + 544, wv, rlane, ph);

    {   // final 264->2 dot: 512 threads = 64 rows x 2 cols x 4 k-quarters
        const int r = tid >> 3, rem = tid & 7;
        const int c = rem >> 2, h = rem & 3;
        const float* wp = &W4s[c * 264];
        const int swr = (r & 7) << 4;
        const int k0 = (h == 0) ? 0 : (8 + 64 * h);       // {0,72,136,200}
        const int k1 = k0 + ((h == 0) ? 72 : 64);
        float s = 0.f;
        for (int k = k0; k < k1; k += 8) {
            uint4 u = *(const uint4*)(actb + r * ACT_RB + ((2 * k) ^ swr));
            float4 wa = *(const float4*)&wp[k];
            float4 wb2 = *(const float4*)&wp[k + 4];
            s = fmaf(bflo(u.x), wa.x, s); s = fmaf(bfhi(u.x), wa.y, s);
            s = fmaf(bflo(u.y), wa.z, s); s = fmaf(bfhi(u.y), wa.w, s);
            s = fmaf(bflo(u.z), wb2.x, s); s = fmaf(bfhi(u.z), wb2.y, s);
            s = fmaf(bflo(u.w), wb2.z, s); s = fmaf(bfhi(u.w), wb2.w, s);
        }
        lsm[tid] = s;
    }
    __syncthreads();
    if (tid < 64) {
        float l0 = lsm[tid * 8 + 0] + lsm[tid * 8 + 1] + lsm[tid * 8 + 2] + lsm[tid * 8 + 3] + W4s[528];
        float l1 = lsm[tid * 8 + 4] + lsm[tid * 8 + 5] + lsm[tid * 8 + 6] + lsm[tid * 8 + 7] + W4s[529];
        float m = fmaxf(l0, l1);
        float lse = m + __logf(__expf(l0 - m) + __expf(l1 - m));
        float2 o; o.x = l0 - lse; o.y = l1 - lse;
        *(float2*)&outp[(row0 + tid) * 2] = o;
    }
}

// ---------------------------------------------------------------------------
extern "C" void kernel_launch(void* const* d_in, const int* in_sizes, int n_in,
                              void* d_out, int out_size, void* d_ws, size_t ws_size,
                              hipStream_t stream)
{
    const float* x    = (const float*)d_in[0];
    const float* c1W1 = (const float*)d_in[2];
    const float* c1b1 = (const float*)d_in[3];
    const float* c1W2 = (const float*)d_in[4];
    const float* c1b2 = (const float*)d_in[5];
    const float* c2W1 = (const float*)d_in[6];
    const float* c2b1 = (const float*)d_in[7];
    const float* c2W2 = (const float*)d_in[8];
    const float* c2b2 = (const float*)d_in[9];
    const float* c3W1 = (const float*)d_in[10];
    const float* c3b1 = (const float*)d_in[11];
    const float* c3W2 = (const float*)d_in[12];
    const float* c3b2 = (const float*)d_in[13];
    const float* mW1  = (const float*)d_in[14];
    const float* mb1  = (const float*)d_in[15];
    const float* mW2  = (const float*)d_in[16];
    const float* mb2  = (const float*)d_in[17];
    const float* mW3  = (const float*)d_in[18];
    const float* mb3  = (const float*)d_in[19];
    const float* mW4  = (const float*)d_in[20];
    const float* mb4  = (const float*)d_in[21];

    // workspace carve (~70 MB)
    float* x1 = (float*)d_ws;                                        // [N,32] f32
    float* x2 = x1 + (size_t)NROWS * 32;                             // [N,32] f32
    __hip_bfloat16* x3 = (__hip_bfloat16*)(x2 + (size_t)NROWS * 32); // [N,64] bf16
    int* nidx = (int*)(x3 + (size_t)NROWS * 64);                     // [N,4] i32
    __hip_bfloat16* WT1 = (__hip_bfloat16*)(nidx + (size_t)NROWS * 4);
    __hip_bfloat16* WT2 = WT1 + 272 * 136;
    __hip_bfloat16* WT3 = WT2 + 272 * 296;
    float* bp = (float*)(WT3 + 272 * 296);                           // [3][272] f32
    __hip_bfloat16* xph = (__hip_bfloat16*)(bp + 3 * 272);           // [N,32] bf16
    __hip_bfloat16* xpl = xph + (size_t)NROWS * 32;                  // [N,32] bf16
    float* sqw = (float*)(xpl + (size_t)NROWS * 32);                 // [N] f32
    __hip_bfloat16* E11 = (__hip_bfloat16*)(sqw + NROWS);            // [32][32]
    __hip_bfloat16* E12 = E11 + 32 * 32;                             // [32][64]
    __hip_bfloat16* E13 = E12 + 32 * 64;                             // [64][64]
    __hip_bfloat16* E21 = E13 + 64 * 64;                             // [32][32]
    __hip_bfloat16* E22 = E21 + 32 * 32;                             // [32][32]
    __hip_bfloat16* E23 = E22 + 32 * 32;                             // [64][64]

    prep_kernel<<<dim3(512), 256, 0, stream>>>(mW1, mW2, mW3, mb1, mb2, mb3,
                                               c1W1, c1W2, c2W1, c2W2, c3W1, c3W2,
                                               WT1, WT2, WT3, bp,
                                               E11, E12, E13, E21, E22, E23);

    dim3 kgrid(PP / 64, BB);
    dim3 pgrid(NROWS * 4 / 256);
    dim3 egrid(NROWS / 64);

    pack_kernel<<<pgrid, 256, 0, stream>>>(x, 1, xph, xpl, sqw);
    knn_mfma<<<kgrid, 256, 0, stream>>>(xph, xpl, sqw, nidx);
    edge_mfma<1, 32, 32, float, true><<<egrid, 256, 0, stream>>>(
        x, nidx, E11, E21, c1b1, c1b2, x1, xph, xpl, sqw);

    knn_mfma<<<kgrid, 256, 0, stream>>>(xph, xpl, sqw, nidx);
    edge_mfma<32, 32, 32, float, true><<<egrid, 256, 0, stream>>>(
        x1, nidx, E12, E22, c2b1, c2b2, x2, xph, xpl, sqw);

    knn_mfma<<<kgrid, 256, 0, stream>>>(xph, xpl, sqw, nidx);
    edge_mfma<32, 64, 64, __hip_bfloat16, false><<<egrid, 256, 0, stream>>>(
        x2, nidx, E13, E23, c3b1, c3b2, x3, nullptr, nullptr, nullptr);

    mlp_kernel<<<dim3(NROWS / 64), 512, 0, stream>>>(x1, x2, x3, WT1, WT2, WT3, bp,
                                                     mW4, mb4, (float*)d_out);
}